// Round 8
// baseline (339.202 us; speedup 1.0000x reference)
//
#include <hip/hip_runtime.h>
#include <hip/hip_bf16.h>
#include <stdint.h>

#define S_LEN 2048
#define DMODEL 1024
#define NH 16
#define DK 64
#define BATCH 4
#define KDIM 1024
#define SCQ 0.18033688f  // (1/8) * log2(e), folded into Wq/bq

using bf16 = __hip_bfloat16;
using bf162 = __hip_bfloat162;

typedef __bf16 v_bf16x8 __attribute__((ext_vector_type(8)));
typedef short v_s16x4 __attribute__((ext_vector_type(4)));
typedef float v_f32x4 __attribute__((ext_vector_type(4)));

union PackB4 { v_s16x4 v; bf162 h[2]; };
struct alignas(16) S16x8 { v_s16x4 lo, hi; };

// pack 8 consecutive fp32 -> 8 bf16 (one 16B value)
__device__ __forceinline__ S16x8 pack8(const float* src) {
    float4 f0 = *(const float4*)src;
    float4 f1 = *(const float4*)(src + 4);
    PackB4 a, b;
    a.h[0] = __float22bfloat162_rn(make_float2(f0.x, f0.y));
    a.h[1] = __float22bfloat162_rn(make_float2(f0.z, f0.w));
    b.h[0] = __float22bfloat162_rn(make_float2(f1.x, f1.y));
    b.h[1] = __float22bfloat162_rn(make_float2(f1.z, f1.w));
    S16x8 r; r.lo = a.v; r.hi = b.v;
    return r;
}

// ---------- prep: W[k][n] fp32 -> Wt[n][k] bf16 (scaled) ----------
__global__ __launch_bounds__(256) void transpose_cvt(const float* __restrict__ W,
                                                     bf16* __restrict__ Wt, float sc) {
    __shared__ float tile[32][33];
    int tx = threadIdx.x, ty = threadIdx.y;
    int k0 = blockIdx.x * 32, n0 = blockIdx.y * 32;
    #pragma unroll
    for (int i = 0; i < 4; i++) {
        int k = k0 + ty + 8 * i;
        tile[ty + 8 * i][tx] = W[(size_t)k * DMODEL + n0 + tx];
    }
    __syncthreads();
    #pragma unroll
    for (int i = 0; i < 4; i++) {
        int n = n0 + ty + 8 * i;
        Wt[(size_t)n * DMODEL + k0 + tx] = __float2bfloat16(tile[tx][ty + 8 * i] * sc);
    }
}

// ---------- MFMA projection GEMM: C = x(fp32) @ W + bias*bscale ----------
// X: [8192,1024] fp32 row-major (converted to bf16 on the fly during staging).
// Bt[n][k] bf16 (pre-scaled). MODE 1: C bf16 as [B,H,S,DK]. MODE 2 (V^T):
// operand-swapped, C bf16 as [B,H,DK,S] with coalesced stores.
template <int MODE>
__global__ __launch_bounds__(256) void gemm_projF(
    const float* __restrict__ X, const bf16* __restrict__ Bt,
    const float* __restrict__ bias, float bscale, bf16* __restrict__ C)
{
    __shared__ __align__(16) short As[128 * 32];
    __shared__ __align__(16) short Bs[128 * 32];
    const int t = threadIdx.x;
    const int lane = t & 63;
    const int wave = t >> 6;
    const int quad = lane >> 4;
    const int l15 = lane & 15;
    const int m0 = blockIdx.x * 128;
    const int n0 = blockIdx.y * 128;
    const int wRow = (wave >> 1) * 64;
    const int wCol = (wave & 1) * 64;

    const int r0 = t >> 2, p0 = t & 3;
    const int r1 = (t + 256) >> 2, p1 = (t + 256) & 3;

    v_f32x4 acc[4][4] = {};

    for (int k0 = 0; k0 < KDIM; k0 += 32) {
        S16x8 a0 = pack8(X + (size_t)(m0 + r0) * KDIM + k0 + p0 * 8);
        S16x8 a1 = pack8(X + (size_t)(m0 + r1) * KDIM + k0 + p1 * 8);
        uint4 b0 = *(const uint4*)(Bt + (size_t)(n0 + r0) * KDIM + k0 + p0 * 8);
        uint4 b1 = *(const uint4*)(Bt + (size_t)(n0 + r1) * KDIM + k0 + p1 * 8);
        __syncthreads();
        *(S16x8*)(As + r0 * 32 + p0 * 8) = a0;
        *(S16x8*)(As + r1 * 32 + p1 * 8) = a1;
        *(uint4*)(Bs + r0 * 32 + p0 * 8) = b0;
        *(uint4*)(Bs + r1 * 32 + p1 * 8) = b1;
        __syncthreads();

        v_bf16x8 af[4], bfr[4];
        #pragma unroll
        for (int mt = 0; mt < 4; mt++) {
            int r = wRow + mt * 16 + l15;
            af[mt] = *(const v_bf16x8*)((MODE == 2 ? Bs : As) + r * 32 + quad * 8);
        }
        #pragma unroll
        for (int nt = 0; nt < 4; nt++) {
            int r = wCol + nt * 16 + l15;
            bfr[nt] = *(const v_bf16x8*)((MODE == 2 ? As : Bs) + r * 32 + quad * 8);
        }
        #pragma unroll
        for (int mt = 0; mt < 4; mt++)
            #pragma unroll
            for (int nt = 0; nt < 4; nt++)
                acc[mt][nt] = __builtin_amdgcn_mfma_f32_16x16x32_bf16(
                    af[mt], bfr[nt], acc[mt][nt], 0, 0, 0);
    }

    if (MODE == 1) {
        float bvv[4];
        #pragma unroll
        for (int nt = 0; nt < 4; nt++)
            bvv[nt] = bias[n0 + wCol + nt * 16 + l15] * bscale;
        #pragma unroll
        for (int mt = 0; mt < 4; mt++)
            #pragma unroll
            for (int nt = 0; nt < 4; nt++)
                #pragma unroll
                for (int r = 0; r < 4; r++) {
                    int row = m0 + wRow + mt * 16 + quad * 4 + r;
                    int col = n0 + wCol + nt * 16 + l15;
                    int b = row >> 11, s = row & (S_LEN - 1);
                    int h = col >> 6, dk = col & (DK - 1);
                    C[(((size_t)(b * NH + h)) * S_LEN + s) * DK + dk] =
                        __float2bfloat16(acc[mt][nt][r] + bvv[nt]);
                }
    } else {
        // rows = n (dk dim), cols = s -> contiguous-s stores into Vt[b,h,dk,s]
        float bvv[4][4];
        #pragma unroll
        for (int mt = 0; mt < 4; mt++)
            #pragma unroll
            for (int r = 0; r < 4; r++)
                bvv[mt][r] = bias[n0 + wRow + mt * 16 + quad * 4 + r];
        #pragma unroll
        for (int mt = 0; mt < 4; mt++)
            #pragma unroll
            for (int nt = 0; nt < 4; nt++)
                #pragma unroll
                for (int r = 0; r < 4; r++) {
                    int ng = n0 + wRow + mt * 16 + quad * 4 + r;
                    int rowg = m0 + wCol + nt * 16 + l15;
                    int b = rowg >> 11, s = rowg & (S_LEN - 1);
                    int h = ng >> 6, dk = ng & (DK - 1);
                    C[(((size_t)(b * NH + h)) * DK + dk) * S_LEN + s] =
                        __float2bfloat16(acc[mt][nt][r] + bvv[mt][r]);
                }
    }
}

// ---------- output projection: out = AO(bf16) @ Wo + bo (fp32 out) ----------
__global__ __launch_bounds__(256) void gemm_o(
    const bf16* __restrict__ A, const bf16* __restrict__ Bt,
    const float* __restrict__ bias, float* __restrict__ C)
{
    __shared__ __align__(16) short As[128 * 32];
    __shared__ __align__(16) short Bs[128 * 32];
    const int t = threadIdx.x;
    const int lane = t & 63;
    const int wave = t >> 6;
    const int quad = lane >> 4;
    const int l15 = lane & 15;
    const int m0 = blockIdx.x * 128;
    const int n0 = blockIdx.y * 128;
    const int wRow = (wave >> 1) * 64;
    const int wCol = (wave & 1) * 64;

    const int r0 = t >> 2, p0 = t & 3;
    const int r1 = (t + 256) >> 2, p1 = (t + 256) & 3;

    v_f32x4 acc[4][4] = {};

    for (int k0 = 0; k0 < KDIM; k0 += 32) {
        uint4 a0 = *(const uint4*)(A + (size_t)(m0 + r0) * KDIM + k0 + p0 * 8);
        uint4 a1 = *(const uint4*)(A + (size_t)(m0 + r1) * KDIM + k0 + p1 * 8);
        uint4 b0 = *(const uint4*)(Bt + (size_t)(n0 + r0) * KDIM + k0 + p0 * 8);
        uint4 b1 = *(const uint4*)(Bt + (size_t)(n0 + r1) * KDIM + k0 + p1 * 8);
        __syncthreads();
        *(uint4*)(As + r0 * 32 + p0 * 8) = a0;
        *(uint4*)(As + r1 * 32 + p1 * 8) = a1;
        *(uint4*)(Bs + r0 * 32 + p0 * 8) = b0;
        *(uint4*)(Bs + r1 * 32 + p1 * 8) = b1;
        __syncthreads();

        v_bf16x8 af[4], bfr[4];
        #pragma unroll
        for (int mt = 0; mt < 4; mt++) {
            int r = wRow + mt * 16 + l15;
            af[mt] = *(const v_bf16x8*)(As + r * 32 + quad * 8);
        }
        #pragma unroll
        for (int nt = 0; nt < 4; nt++) {
            int r = wCol + nt * 16 + l15;
            bfr[nt] = *(const v_bf16x8*)(Bs + r * 32 + quad * 8);
        }
        #pragma unroll
        for (int mt = 0; mt < 4; mt++)
            #pragma unroll
            for (int nt = 0; nt < 4; nt++)
                acc[mt][nt] = __builtin_amdgcn_mfma_f32_16x16x32_bf16(
                    af[mt], bfr[nt], acc[mt][nt], 0, 0, 0);
    }

    float bvv[4];
    #pragma unroll
    for (int nt = 0; nt < 4; nt++) bvv[nt] = bias[n0 + wCol + nt * 16 + l15];

    #pragma unroll
    for (int mt = 0; mt < 4; mt++)
        #pragma unroll
        for (int nt = 0; nt < 4; nt++)
            #pragma unroll
            for (int r = 0; r < 4; r++) {
                int row = m0 + wRow + mt * 16 + quad * 4 + r;
                int col = n0 + wCol + nt * 16 + l15;
                C[(size_t)row * DMODEL + col] = acc[mt][nt][r] + bvv[nt];
            }
}

// ---------------- MFMA flash attention (causal), register-P PV ----------------
// Q,K: [B,H,S,DK] bf16 (Q pre-scaled).  Vt: [B,H,DK,S] bf16.  Out: [B,S,H,DK] bf16.
// S^T = K@Q^T (16x16x32; C/D col=query,row=key) feeds PV from registers as the
// B-operand of mfma_16x16x16bf16_1k: O^T = V^T @ P^T.
__global__ __launch_bounds__(256) void attn_mfma(
    const bf16* __restrict__ Qg, const bf16* __restrict__ Kg,
    const bf16* __restrict__ Vtg, bf16* __restrict__ Og)
{
    __shared__ __align__(16) short lds[16384];   // 32 KiB
    short* Ks = lds;          // [128][64], 8-chunk XOR swizzle (16 KiB)
    short* Vs = lds + 8192;   // [64][128], 16-chunk XOR swizzle (16 KiB)
    // epilogue reuses lds as Ot[128][72]

    const int t = threadIdx.x;
    const int lane = t & 63;
    const int wave = t >> 6;
    const int quad = lane >> 4;
    const int l15 = lane & 15;
    const int bh = blockIdx.x;
    const int yy = (gridDim.y - 1) - blockIdx.y;  // biggest blocks first
    const int q0 = yy * 128;

    const size_t baseK = (size_t)bh * S_LEN * DK;
    const size_t baseVt = (size_t)bh * DK * S_LEN;

    v_bf16x8 qf[2][2];
    #pragma unroll
    for (int qt = 0; qt < 2; qt++) {
        int q = q0 + wave * 32 + qt * 16 + l15;
        #pragma unroll
        for (int kc = 0; kc < 2; kc++)
            qf[qt][kc] = *(const v_bf16x8*)(Qg + baseK + (size_t)q * DK + kc * 32 + quad * 8);
    }

    v_f32x4 oacc[2][4] = {};              // O^T: [qt][dt], rows=d(quad*4+r), cols=q(l15)
    float mrun[2] = {-1e30f, -1e30f};
    float lrun[2] = {0.f, 0.f};

    for (int tt = 0; tt <= yy; tt++) {
        int k0 = tt * 128;
        __syncthreads();
        #pragma unroll
        for (int i = 0; i < 4; i++) {
            int c = t + 256 * i;
            int r = c >> 3, p = c & 7;
            uint4 val = *(const uint4*)(Kg + baseK + (size_t)(k0 + r) * DK + p * 8);
            *(uint4*)(Ks + r * 64 + (p ^ (r & 7)) * 8) = val;
        }
        #pragma unroll
        for (int i = 0; i < 4; i++) {
            int c = t + 256 * i;
            int d = c >> 4, p = c & 15;
            uint4 val = *(const uint4*)(Vtg + baseVt + (size_t)d * S_LEN + k0 + p * 8);
            *(uint4*)(Vs + d * 128 + ((p ^ (d & 15)) << 3)) = val;
        }
        __syncthreads();

        // ---- S^T = K @ Q^T (rows=key, cols=query); Q pre-scaled -> log2-units
        v_f32x4 s_[8][2];
        #pragma unroll
        for (int kt = 0; kt < 8; kt++) {
            int krow = kt * 16 + l15;
            v_bf16x8 kf0 = *(const v_bf16x8*)(Ks + krow * 64 + ((quad) ^ (krow & 7)) * 8);
            v_bf16x8 kf1 = *(const v_bf16x8*)(Ks + krow * 64 + ((4 + quad) ^ (krow & 7)) * 8);
            #pragma unroll
            for (int qt = 0; qt < 2; qt++) {
                v_f32x4 a = {};
                a = __builtin_amdgcn_mfma_f32_16x16x32_bf16(kf0, qf[qt][0], a, 0, 0, 0);
                a = __builtin_amdgcn_mfma_f32_16x16x32_bf16(kf1, qf[qt][1], a, 0, 0, 0);
                s_[kt][qt] = a;
            }
        }

        if (tt == yy) {  // causal mask, diagonal tile only
            #pragma unroll
            for (int kt = 0; kt < 8; kt++)
                #pragma unroll
                for (int qt = 0; qt < 2; qt++) {
                    int qq = wave * 32 + qt * 16 + l15;
                    #pragma unroll
                    for (int r = 0; r < 4; r++) {
                        int key = kt * 16 + quad * 4 + r;
                        if (key > qq) s_[kt][qt][r] = -1e30f;
                    }
                }
        }

        float tmax[2] = {-1e30f, -1e30f};
        #pragma unroll
        for (int kt = 0; kt < 8; kt++)
            #pragma unroll
            for (int qt = 0; qt < 2; qt++)
                #pragma unroll
                for (int r = 0; r < 4; r++)
                    tmax[qt] = fmaxf(tmax[qt], s_[kt][qt][r]);
        #pragma unroll
        for (int qt = 0; qt < 2; qt++) {
            tmax[qt] = fmaxf(tmax[qt], __shfl_xor(tmax[qt], 16));
            tmax[qt] = fmaxf(tmax[qt], __shfl_xor(tmax[qt], 32));
        }
        float alpha[2];
        #pragma unroll
        for (int qt = 0; qt < 2; qt++) {
            float mn = fmaxf(mrun[qt], tmax[qt]);
            alpha[qt] = __builtin_amdgcn_exp2f(mrun[qt] - mn);
            mrun[qt] = mn;
        }
        float lsum[2] = {0.f, 0.f};
        #pragma unroll
        for (int kt = 0; kt < 8; kt++)
            #pragma unroll
            for (int qt = 0; qt < 2; qt++)
                #pragma unroll
                for (int r = 0; r < 4; r++) {
                    float p = __builtin_amdgcn_exp2f(s_[kt][qt][r] - mrun[qt]);
                    s_[kt][qt][r] = p;
                    lsum[qt] += p;
                }
        #pragma unroll
        for (int qt = 0; qt < 2; qt++) {
            lsum[qt] += __shfl_xor(lsum[qt], 16);
            lsum[qt] += __shfl_xor(lsum[qt], 32);
            lrun[qt] = lrun[qt] * alpha[qt] + lsum[qt];
        }
        #pragma unroll
        for (int qt = 0; qt < 2; qt++)
            #pragma unroll
            for (int dt = 0; dt < 4; dt++)
                #pragma unroll
                for (int r = 0; r < 4; r++)
                    oacc[qt][dt][r] *= alpha[qt];

        // ---- PV: O^T += V^T @ P^T (P from registers, K=16 MFMA)
        #pragma unroll
        for (int kt = 0; kt < 8; kt++) {
            v_s16x4 vf[4];
            #pragma unroll
            for (int dt = 0; dt < 4; dt++) {
                int d = dt * 16 + l15;
                int ch = (2 * kt + (quad >> 1)) ^ (d & 15);
                vf[dt] = *(const v_s16x4*)(Vs + d * 128 + (ch << 3) + (quad & 1) * 4);
            }
            #pragma unroll
            for (int qt = 0; qt < 2; qt++) {
                PackB4 pu;
                pu.h[0] = __float22bfloat162_rn(make_float2(s_[kt][qt][0], s_[kt][qt][1]));
                pu.h[1] = __float22bfloat162_rn(make_float2(s_[kt][qt][2], s_[kt][qt][3]));
                #pragma unroll
                for (int dt = 0; dt < 4; dt++)
                    oacc[qt][dt] = __builtin_amdgcn_mfma_f32_16x16x16bf16_1k(
                        vf[dt], pu.v, oacc[qt][dt], 0, 0, 0);
            }
        }
    }

    // ---- epilogue: O^T -> Ot[q][d] in LDS (stride 72), then coalesced store
    __syncthreads();  // Ks/Vs dead for all waves before aliasing as Ot
    #pragma unroll
    for (int qt = 0; qt < 2; qt++) {
        float inv = 1.f / lrun[qt];
        int qloc = wave * 32 + qt * 16 + l15;
        #pragma unroll
        for (int dt = 0; dt < 4; dt++) {
            PackB4 ou;
            ou.h[0] = __float22bfloat162_rn(
                make_float2(oacc[qt][dt][0] * inv, oacc[qt][dt][1] * inv));
            ou.h[1] = __float22bfloat162_rn(
                make_float2(oacc[qt][dt][2] * inv, oacc[qt][dt][3] * inv));
            *(v_s16x4*)(lds + qloc * 72 + dt * 16 + quad * 4) = ou.v;
        }
    }
    __syncthreads();
    {
        const int b = bh >> 4, h = bh & 15;
        int row = t >> 1, half = t & 1;
        size_t gbase = (((size_t)b * S_LEN + q0 + row) * NH + h) * DK + half * 32;
        #pragma unroll
        for (int j = 0; j < 4; j++)
            *(uint4*)(Og + gbase + j * 8) =
                *(const uint4*)(lds + row * 72 + half * 32 + j * 8);
    }
}

extern "C" void kernel_launch(void* const* d_in, const int* in_sizes, int n_in,
                              void* d_out, int out_size, void* d_ws, size_t ws_size,
                              hipStream_t stream) {
    const float* x  = (const float*)d_in[0];
    // d_in[1] = attn_mask (tril) — causality implemented directly
    const float* Wq = (const float*)d_in[2];
    const float* bq = (const float*)d_in[3];
    const float* Wk = (const float*)d_in[4];
    const float* bk = (const float*)d_in[5];
    const float* Wv = (const float*)d_in[6];
    const float* bv = (const float*)d_in[7];
    const float* Wo = (const float*)d_in[8];
    const float* bo = (const float*)d_in[9];
    float* out = (float*)d_out;

    // ws layout (exactly 64 MiB), d_out NEVER used as scratch:
    //  [0,16)   Q   [B,H,S,DK] bf16
    //  [16,32)  Kt  [B,H,S,DK] bf16
    //  [32,48)  Vt  [B,H,DK,S] bf16   (first 2 MiB becomes WtO after attn)
    //  [48,64)  WtQ/WtK/WtV (2 MiB each) during projections; AO after attn
    const size_t TEN = (size_t)BATCH * S_LEN * DMODEL * sizeof(bf16);  // 16 MiB
    const size_t WSZ = (size_t)DMODEL * DMODEL * sizeof(bf16);         // 2 MiB
    char* ws = (char*)d_ws;
    bf16* Q   = (bf16*)ws;
    bf16* Kt  = (bf16*)(ws + TEN);
    bf16* Vt  = (bf16*)(ws + 2 * TEN);
    bf16* WtO = (bf16*)(ws + 2 * TEN);          // after attn, Vt is dead
    bf16* WtQ = (bf16*)(ws + 3 * TEN);
    bf16* WtK = (bf16*)(ws + 3 * TEN + WSZ);
    bf16* WtV = (bf16*)(ws + 3 * TEN + 2 * WSZ);
    bf16* AO  = (bf16*)(ws + 3 * TEN);          // overwrites WtQ/K/V (dead)

    dim3 gT(DMODEL / 32, DMODEL / 32), bT(32, 8);
    dim3 gG(BATCH * S_LEN / 128, DMODEL / 128);  // (64, 8)

    hipLaunchKernelGGL(transpose_cvt, gT, bT, 0, stream, Wq, WtQ, SCQ);
    hipLaunchKernelGGL(transpose_cvt, gT, bT, 0, stream, Wk, WtK, 1.0f);
    hipLaunchKernelGGL(transpose_cvt, gT, bT, 0, stream, Wv, WtV, 1.0f);

    hipLaunchKernelGGL((gemm_projF<1>), gG, dim3(256), 0, stream, x, WtQ, bq, SCQ, Q);
    hipLaunchKernelGGL((gemm_projF<1>), gG, dim3(256), 0, stream, x, WtK, bk, 1.0f, Kt);
    hipLaunchKernelGGL((gemm_projF<2>), gG, dim3(256), 0, stream, x, WtV, bv, 1.0f, Vt);

    hipLaunchKernelGGL(attn_mfma, dim3(BATCH * NH, S_LEN / 128), dim3(256),
                       0, stream, Q, Kt, Vt, AO);

    hipLaunchKernelGGL(transpose_cvt, gT, bT, 0, stream, Wo, WtO, 1.0f);
    hipLaunchKernelGGL(gemm_o, gG, dim3(256), 0, stream, AO, WtO, bo, out);
}